// Round 1
// baseline (1692.561 us; speedup 1.0000x reference)
//
#include <hip/hip_runtime.h>

// out[row][c] = act( sum_k A[row][k] * W[k][c] + bias[c] )
// A: [nrows, K] row-major, W: [K, 128] row-major, out: [nrows, 128].
// Block = 256 threads; thread t: lane = t&63 -> cols {2*lane, 2*lane+1},
// group = t>>6 -> 8 rows starting at blockIdx*32 + group*8.
// W loads: float2, coalesced across the wave (512B/instr), L1/L2-hot.
// A loads: float4, wave-uniform address (broadcast), L1-hot within row tile.
template<int K, bool RELU>
__global__ __launch_bounds__(256) void gemm_bias(const float* __restrict__ A,
                                                 const float* __restrict__ W,
                                                 const float* __restrict__ bias,
                                                 float* __restrict__ out,
                                                 int nrows) {
  const int t = threadIdx.x;
  const int lane = t & 63;
  const int grp = t >> 6;
  const int c0 = lane * 2;
  const int r0 = blockIdx.x * 32 + grp * 8;

  float2 acc[8];
#pragma unroll
  for (int r = 0; r < 8; ++r) acc[r] = make_float2(0.f, 0.f);

  int rowc[8];
#pragma unroll
  for (int r = 0; r < 8; ++r) {
    int row = r0 + r;
    rowc[r] = row < nrows ? row : (nrows - 1);  // clamp loads, guard stores
  }

  for (int k = 0; k < K; k += 4) {
    float2 w0 = *(const float2*)(W + (k + 0) * 128 + c0);
    float2 w1 = *(const float2*)(W + (k + 1) * 128 + c0);
    float2 w2 = *(const float2*)(W + (k + 2) * 128 + c0);
    float2 w3 = *(const float2*)(W + (k + 3) * 128 + c0);
#pragma unroll
    for (int r = 0; r < 8; ++r) {
      float4 f = *(const float4*)(A + (size_t)rowc[r] * K + k);
      acc[r].x = fmaf(f.x, w0.x, acc[r].x);
      acc[r].y = fmaf(f.x, w0.y, acc[r].y);
      acc[r].x = fmaf(f.y, w1.x, acc[r].x);
      acc[r].y = fmaf(f.y, w1.y, acc[r].y);
      acc[r].x = fmaf(f.z, w2.x, acc[r].x);
      acc[r].y = fmaf(f.z, w2.y, acc[r].y);
      acc[r].x = fmaf(f.w, w3.x, acc[r].x);
      acc[r].y = fmaf(f.w, w3.y, acc[r].y);
    }
  }

  float2 b = *(const float2*)(bias + c0);
#pragma unroll
  for (int r = 0; r < 8; ++r) {
    int row = r0 + r;
    if (row < nrows) {
      float2 v = make_float2(acc[r].x + b.x, acc[r].y + b.y);
      if (RELU) { v.x = fmaxf(v.x, 0.f); v.y = fmaxf(v.y, 0.f); }
      *(float2*)(out + (size_t)row * 128 + c0) = v;
    }
  }
}

// 32 threads per edge: thread-part p handles elems 4p..4p+3.
// Gather x[src] (contiguous 512B per edge across the 32 lanes),
// scale by edge weight, atomicAdd into agg[dst].
__global__ __launch_bounds__(256) void scatter_add(const float* __restrict__ x,
                                                   const int* __restrict__ ei,
                                                   const float* __restrict__ ew,
                                                   float* __restrict__ agg,
                                                   int E) {
  long g = (long)blockIdx.x * 256 + threadIdx.x;
  long total = (long)E * 32;
  if (g >= total) return;
  int e = (int)(g >> 5);
  int p = (int)(g & 31);
  int src = ei[e];
  int dst = ei[E + e];
  float w = ew[e];
  float4 v = *(const float4*)(x + (size_t)src * 128 + p * 4);
  float* a = agg + (size_t)dst * 128 + p * 4;
  atomicAdd(a + 0, v.x * w);
  atomicAdd(a + 1, v.y * w);
  atomicAdd(a + 2, v.z * w);
  atomicAdd(a + 3, v.w * w);
}

extern "C" void kernel_launch(void* const* d_in, const int* in_sizes, int n_in,
                              void* d_out, int out_size, void* d_ws, size_t ws_size,
                              hipStream_t stream) {
  const float* features = (const float*)d_in[0];
  const int* ei = (const int*)d_in[1];   // [2, E] int32
  const float* ew = (const float*)d_in[2];
  const float* Wp = (const float*)d_in[3];
  const float* bp = (const float*)d_in[4];
  const float* Wa = (const float*)d_in[5];
  const float* ba = (const float*)d_in[6];

  const int N = in_sizes[0] / 256;  // 50000
  const int E = in_sizes[1] / 2;    // 800000

  float* out = (float*)d_out;
  float* x   = out;                 // [N,128] scratch lives in d_out until GEMM2
  float* agg = (float*)d_ws;        // [N,128] in workspace (25.6 MB)

  // agg must be zeroed every call (ws is poisoned once, never re-poisoned).
  hipMemsetAsync(agg, 0, (size_t)N * 128 * sizeof(float), stream);

  // 1) x = features @ W_proj + b_proj
  gemm_bias<256, false><<<(N + 31) / 32, 256, 0, stream>>>(features, Wp, bp, x, N);

  // 2) agg[dst] += w_e * x[src]
  long total = (long)E * 32;
  int blocks = (int)((total + 255) / 256);
  scatter_add<<<blocks, 256, 0, stream>>>(x, ei, ew, agg, E);

  // 3) out = relu(agg @ W_agg + b_agg)   (overwrites the x scratch)
  gemm_bias<128, true><<<(N + 31) / 32, 256, 0, stream>>>(agg, Wa, ba, out, N);
}

// Round 2
// 606.786 us; speedup vs baseline: 2.7894x; 2.7894x over previous
//
#include <hip/hip_runtime.h>

// ---------------- GEMM (+bias, optional relu), fp32 VALU ----------------
// out[row][c] = act( sum_k A[row][k] * W[k][c] + bias[c] )
// Block = 256 threads; thread t: lane = t&63 -> cols {2*lane, 2*lane+1},
// group = t>>6 -> 8 rows starting at blockIdx*32 + group*8.
template<int K, bool RELU>
__global__ __launch_bounds__(256) void gemm_bias(const float* __restrict__ A,
                                                 const float* __restrict__ W,
                                                 const float* __restrict__ bias,
                                                 float* __restrict__ out,
                                                 int nrows) {
  const int t = threadIdx.x;
  const int lane = t & 63;
  const int grp = t >> 6;
  const int c0 = lane * 2;
  const int r0 = blockIdx.x * 32 + grp * 8;

  float2 acc[8];
#pragma unroll
  for (int r = 0; r < 8; ++r) acc[r] = make_float2(0.f, 0.f);

  int rowc[8];
#pragma unroll
  for (int r = 0; r < 8; ++r) {
    int row = r0 + r;
    rowc[r] = row < nrows ? row : (nrows - 1);  // clamp loads, guard stores
  }

  for (int k = 0; k < K; k += 4) {
    float2 w0 = *(const float2*)(W + (k + 0) * 128 + c0);
    float2 w1 = *(const float2*)(W + (k + 1) * 128 + c0);
    float2 w2 = *(const float2*)(W + (k + 2) * 128 + c0);
    float2 w3 = *(const float2*)(W + (k + 3) * 128 + c0);
#pragma unroll
    for (int r = 0; r < 8; ++r) {
      float4 f = *(const float4*)(A + (size_t)rowc[r] * K + k);
      acc[r].x = fmaf(f.x, w0.x, acc[r].x);
      acc[r].y = fmaf(f.x, w0.y, acc[r].y);
      acc[r].x = fmaf(f.y, w1.x, acc[r].x);
      acc[r].y = fmaf(f.y, w1.y, acc[r].y);
      acc[r].x = fmaf(f.z, w2.x, acc[r].x);
      acc[r].y = fmaf(f.z, w2.y, acc[r].y);
      acc[r].x = fmaf(f.w, w3.x, acc[r].x);
      acc[r].y = fmaf(f.w, w3.y, acc[r].y);
    }
  }

  float2 b = *(const float2*)(bias + c0);
#pragma unroll
  for (int r = 0; r < 8; ++r) {
    int row = r0 + r;
    if (row < nrows) {
      float2 v = make_float2(acc[r].x + b.x, acc[r].y + b.y);
      if (RELU) { v.x = fmaxf(v.x, 0.f); v.y = fmaxf(v.y, 0.f); }
      *(float2*)(out + (size_t)row * 128 + c0) = v;
    }
  }
}

// ---------------- CSR build: count -> scan -> fill ----------------
__global__ __launch_bounds__(256) void edge_count(const int* __restrict__ ei,
                                                  int* __restrict__ cnt, int E) {
  for (int e = blockIdx.x * 256 + threadIdx.x; e < E; e += gridDim.x * 256)
    atomicAdd(&cnt[ei[E + e]], 1);
}

// Single-block exclusive scan over N counters -> off[0..N], cursor copy.
__global__ __launch_bounds__(1024) void scan_off(const int* __restrict__ cnt,
                                                 int* __restrict__ off,
                                                 int* __restrict__ cursor, int N) {
  __shared__ int s[1024];
  const int tid = threadIdx.x;
  int base = 0;
  for (int c0 = 0; c0 < N; c0 += 1024) {
    int i = c0 + tid;
    int v = (i < N) ? cnt[i] : 0;
    s[tid] = v;
    __syncthreads();
#pragma unroll
    for (int ofs = 1; ofs < 1024; ofs <<= 1) {
      int tv = (tid >= ofs) ? s[tid - ofs] : 0;
      __syncthreads();
      s[tid] += tv;
      __syncthreads();
    }
    int excl = s[tid] - v;
    if (i < N) { off[i] = base + excl; cursor[i] = base + excl; }
    int total = s[1023];
    __syncthreads();
    base += total;
  }
  if (tid == 0) off[N] = base;
}

__global__ __launch_bounds__(256) void edge_fill(const int* __restrict__ ei,
                                                 int* __restrict__ cursor,
                                                 int* __restrict__ perm, int E) {
  for (int e = blockIdx.x * 256 + threadIdx.x; e < E; e += gridDim.x * 256) {
    int pos = atomicAdd(&cursor[ei[E + e]], 1);
    perm[pos] = e;
  }
}

// ---------------- Gather-accumulate (no atomics) ----------------
// One wave per dst node; lane owns cols {2*lane, 2*lane+1}.
// Reads x[src] rows as 512B coalesced; accumulates in registers.
__global__ __launch_bounds__(256) void gather_agg(const float* __restrict__ x,
                                                  const int* __restrict__ ei,
                                                  const float* __restrict__ ew,
                                                  const int* __restrict__ off,
                                                  const int* __restrict__ perm,
                                                  float* __restrict__ agg, int N, int E) {
  const int d = blockIdx.x * 4 + (threadIdx.x >> 6);
  if (d >= N) return;
  const int lane = threadIdx.x & 63;
  const int c0 = lane * 2;

  int j = off[d];
  const int jend = off[d + 1];
  float2 acc = make_float2(0.f, 0.f);

  for (; j + 4 <= jend; j += 4) {
    int e0 = perm[j + 0], e1 = perm[j + 1], e2 = perm[j + 2], e3 = perm[j + 3];
    int s0 = ei[e0], s1 = ei[e1], s2 = ei[e2], s3 = ei[e3];
    float w0 = ew[e0], w1 = ew[e1], w2 = ew[e2], w3 = ew[e3];
    float2 v0 = *(const float2*)(x + (size_t)s0 * 128 + c0);
    float2 v1 = *(const float2*)(x + (size_t)s1 * 128 + c0);
    float2 v2 = *(const float2*)(x + (size_t)s2 * 128 + c0);
    float2 v3 = *(const float2*)(x + (size_t)s3 * 128 + c0);
    acc.x = fmaf(w0, v0.x, acc.x); acc.y = fmaf(w0, v0.y, acc.y);
    acc.x = fmaf(w1, v1.x, acc.x); acc.y = fmaf(w1, v1.y, acc.y);
    acc.x = fmaf(w2, v2.x, acc.x); acc.y = fmaf(w2, v2.y, acc.y);
    acc.x = fmaf(w3, v3.x, acc.x); acc.y = fmaf(w3, v3.y, acc.y);
  }
  for (; j < jend; ++j) {
    int e = perm[j];
    int s = ei[e];
    float w = ew[e];
    float2 v = *(const float2*)(x + (size_t)s * 128 + c0);
    acc.x = fmaf(w, v.x, acc.x); acc.y = fmaf(w, v.y, acc.y);
  }
  *(float2*)(agg + (size_t)d * 128 + c0) = acc;
}

extern "C" void kernel_launch(void* const* d_in, const int* in_sizes, int n_in,
                              void* d_out, int out_size, void* d_ws, size_t ws_size,
                              hipStream_t stream) {
  const float* features = (const float*)d_in[0];
  const int* ei = (const int*)d_in[1];   // [2, E] int32
  const float* ew = (const float*)d_in[2];
  const float* Wp = (const float*)d_in[3];
  const float* bp = (const float*)d_in[4];
  const float* Wa = (const float*)d_in[5];
  const float* ba = (const float*)d_in[6];

  const int N = in_sizes[0] / 256;  // 50000
  const int E = in_sizes[1] / 2;    // 800000

  float* out = (float*)d_out;
  float* x   = out;                 // [N,128] scratch lives in d_out until GEMM2

  // Workspace layout (all 256B-aligned):
  char* ws = (char*)d_ws;
  float* agg   = (float*)ws;                                   // N*128 f32 = 25.6 MB
  size_t o = (size_t)N * 128 * sizeof(float);
  o = (o + 255) & ~(size_t)255;
  int* cnt     = (int*)(ws + o); o += (size_t)N * 4;           // 200 KB
  o = (o + 255) & ~(size_t)255;
  int* off     = (int*)(ws + o); o += (size_t)(N + 1) * 4;
  o = (o + 255) & ~(size_t)255;
  int* cursor  = (int*)(ws + o); o += (size_t)N * 4;
  o = (o + 255) & ~(size_t)255;
  int* perm    = (int*)(ws + o); o += (size_t)E * 4;           // 3.2 MB

  // counters must be zeroed every call (ws never re-poisoned between replays).
  hipMemsetAsync(cnt, 0, (size_t)N * sizeof(int), stream);

  // 1) x = features @ W_proj + b_proj
  gemm_bias<256, false><<<(N + 31) / 32, 256, 0, stream>>>(features, Wp, bp, x, N);

  // 2) CSR build by dst
  edge_count<<<1024, 256, 0, stream>>>(ei, cnt, E);
  scan_off<<<1, 1024, 0, stream>>>(cnt, off, cursor, N);
  edge_fill<<<1024, 256, 0, stream>>>(ei, cursor, perm, E);

  // 3) agg[d] = sum_{e: dst=d} w_e * x[src_e]   (register accumulate, no atomics)
  gather_agg<<<(N + 3) / 4, 256, 0, stream>>>(x, ei, ew, off, perm, agg, N, E);

  // 4) out = relu(agg @ W_agg + b_agg)   (overwrites the x scratch)
  gemm_bias<128, true><<<(N + 31) / 32, 256, 0, stream>>>(agg, Wa, ba, out, N);
}

// Round 3
// 350.354 us; speedup vs baseline: 4.8310x; 1.7319x over previous
//
#include <hip/hip_runtime.h>

// ---------------- LDS-staged GEMM (+bias, optional relu), fp32 VALU ----------------
// out[row][c] = act( sum_k A[row][k] * W[k][c] + bias[c] )
// Block tile: 64 rows x 128 cols, K staged in chunks of 32 (double-buffered LDS).
// Thread t: cols cg..cg+3 (cg=(t&31)*4), rows rg..rg+7 (rg=(t>>5)*8).
// Staging: thread loads A[r0+sr][sk..sk+3] and A[r0+sr+32][...] (coalesced float4),
// T14 split: issue next-chunk loads -> compute current -> ds_write -> barrier.
template<int K, bool RELU>
__global__ __launch_bounds__(256) void gemm_lds(const float* __restrict__ A,
                                                const float* __restrict__ W,
                                                const float* __restrict__ bias,
                                                float* __restrict__ out, int nrows) {
  constexpr int KC = 32;
  constexpr int NC = K / KC;
  __shared__ float As[2][64 * KC];  // [row][k], 8KB per buffer

  const int t = threadIdx.x;
  const int r0 = blockIdx.x * 64;
  const int sr = t >> 3;          // staging row 0..31 (and +32)
  const int sk = (t & 7) * 4;     // staging k-offset
  const int cg = (t & 31) * 4;    // output col group
  const int rg = (t >> 5) * 8;    // output row group

  int srow0 = r0 + sr;      if (srow0 >= nrows) srow0 = nrows - 1;
  int srow1 = r0 + sr + 32; if (srow1 >= nrows) srow1 = nrows - 1;
  const float* gA0 = A + (size_t)srow0 * K + sk;
  const float* gA1 = A + (size_t)srow1 * K + sk;

  float4 acc[8];
#pragma unroll
  for (int r = 0; r < 8; ++r) acc[r] = make_float4(0.f, 0.f, 0.f, 0.f);

  // prologue: stage chunk 0
  {
    float4 s0 = *(const float4*)(gA0);
    float4 s1 = *(const float4*)(gA1);
    *(float4*)&As[0][sr * KC + sk] = s0;
    *(float4*)&As[0][(sr + 32) * KC + sk] = s1;
  }
  __syncthreads();

  for (int c = 0; c < NC; ++c) {
    float4 s0, s1;
    if (c + 1 < NC) {               // issue next-chunk global loads early
      s0 = *(const float4*)(gA0 + (c + 1) * KC);
      s1 = *(const float4*)(gA1 + (c + 1) * KC);
    }
    const float* Asb = As[c & 1];
    const float* Wc = W + (size_t)c * KC * 128 + cg;
#pragma unroll
    for (int kk = 0; kk < KC; kk += 4) {
      float4 a[8];
#pragma unroll
      for (int r = 0; r < 8; ++r)
        a[r] = *(const float4*)&Asb[(rg + r) * KC + kk];
#pragma unroll
      for (int q = 0; q < 4; ++q) {
        float4 w = *(const float4*)(Wc + (size_t)(kk + q) * 128);
#pragma unroll
        for (int r = 0; r < 8; ++r) {
          float av = (q == 0) ? a[r].x : (q == 1) ? a[r].y : (q == 2) ? a[r].z : a[r].w;
          acc[r].x = fmaf(av, w.x, acc[r].x);
          acc[r].y = fmaf(av, w.y, acc[r].y);
          acc[r].z = fmaf(av, w.z, acc[r].z);
          acc[r].w = fmaf(av, w.w, acc[r].w);
        }
      }
    }
    if (c + 1 < NC) {               // late ds_write (vmcnt wait lands here)
      int b = (c + 1) & 1;
      *(float4*)&As[b][sr * KC + sk] = s0;
      *(float4*)&As[b][(sr + 32) * KC + sk] = s1;
    }
    __syncthreads();
  }

  float4 b4 = *(const float4*)(bias + cg);
#pragma unroll
  for (int r = 0; r < 8; ++r) {
    int row = r0 + rg + r;
    if (row < nrows) {
      float4 v = make_float4(acc[r].x + b4.x, acc[r].y + b4.y,
                             acc[r].z + b4.z, acc[r].w + b4.w);
      if (RELU) {
        v.x = fmaxf(v.x, 0.f); v.y = fmaxf(v.y, 0.f);
        v.z = fmaxf(v.z, 0.f); v.w = fmaxf(v.w, 0.f);
      }
      *(float4*)(out + (size_t)row * 128 + cg) = v;
    }
  }
}

// ---------------- CSR build: count -> hierarchical scan -> fill ----------------
__global__ __launch_bounds__(256) void edge_count(const int* __restrict__ ei,
                                                  int* __restrict__ cnt, int E) {
  for (int e = blockIdx.x * 256 + threadIdx.x; e < E; e += gridDim.x * 256)
    atomicAdd(&cnt[ei[E + e]], 1);
}

// K1: per-block (256 counters) sums
__global__ __launch_bounds__(256) void block_sums(const int* __restrict__ cnt,
                                                  int* __restrict__ bsum, int N) {
  __shared__ int s[4];
  int i = blockIdx.x * 256 + threadIdx.x;
  int v = (i < N) ? cnt[i] : 0;
#pragma unroll
  for (int o = 32; o > 0; o >>= 1) v += __shfl_down(v, o, 64);
  if ((threadIdx.x & 63) == 0) s[threadIdx.x >> 6] = v;
  __syncthreads();
  if (threadIdx.x == 0) bsum[blockIdx.x] = s[0] + s[1] + s[2] + s[3];
}

// K2: single small block scans the block sums (nb <= 256), in-place exclusive
__global__ __launch_bounds__(256) void scan_bsum(int* __restrict__ bsum, int nb) {
  __shared__ int s[256];
  int tid = threadIdx.x;
  int v = (tid < nb) ? bsum[tid] : 0;
  s[tid] = v;
  __syncthreads();
#pragma unroll
  for (int o = 1; o < 256; o <<= 1) {
    int tv = (tid >= o) ? s[tid - o] : 0;
    __syncthreads();
    s[tid] += tv;
    __syncthreads();
  }
  if (tid < nb) bsum[tid] = s[tid] - v;
}

// K3: per-block exclusive scan + block offset -> off & cursor
__global__ __launch_bounds__(256) void scan_fin(const int* __restrict__ cnt,
                                               const int* __restrict__ bsum,
                                               int* __restrict__ off,
                                               int* __restrict__ cursor, int N, int E) {
  __shared__ int s[256];
  int tid = threadIdx.x;
  int i = blockIdx.x * 256 + tid;
  int v = (i < N) ? cnt[i] : 0;
  s[tid] = v;
  __syncthreads();
#pragma unroll
  for (int o = 1; o < 256; o <<= 1) {
    int tv = (tid >= o) ? s[tid - o] : 0;
    __syncthreads();
    s[tid] += tv;
    __syncthreads();
  }
  int excl = s[tid] - v + bsum[blockIdx.x];
  if (i < N) { off[i] = excl; cursor[i] = excl; }
  if (i == N - 1) off[N] = E;
}

__global__ __launch_bounds__(256) void edge_fill(const int* __restrict__ ei,
                                                 int* __restrict__ cursor,
                                                 int* __restrict__ perm, int E) {
  for (int e = blockIdx.x * 256 + threadIdx.x; e < E; e += gridDim.x * 256) {
    int pos = atomicAdd(&cursor[ei[E + e]], 1);
    perm[pos] = e;
  }
}

// ---------------- Gather-accumulate (no atomics) ----------------
// One wave per dst node; lane owns cols {2*lane, 2*lane+1}.
__global__ __launch_bounds__(256) void gather_agg(const float* __restrict__ x,
                                                  const int* __restrict__ ei,
                                                  const float* __restrict__ ew,
                                                  const int* __restrict__ off,
                                                  const int* __restrict__ perm,
                                                  float* __restrict__ agg, int N, int E) {
  const int d = blockIdx.x * 4 + (threadIdx.x >> 6);
  if (d >= N) return;
  const int lane = threadIdx.x & 63;
  const int c0 = lane * 2;

  int j = off[d];
  const int jend = off[d + 1];
  float2 acc = make_float2(0.f, 0.f);

  for (; j + 4 <= jend; j += 4) {
    int e0 = perm[j + 0], e1 = perm[j + 1], e2 = perm[j + 2], e3 = perm[j + 3];
    int s0 = ei[e0], s1 = ei[e1], s2 = ei[e2], s3 = ei[e3];
    float w0 = ew[e0], w1 = ew[e1], w2 = ew[e2], w3 = ew[e3];
    float2 v0 = *(const float2*)(x + (size_t)s0 * 128 + c0);
    float2 v1 = *(const float2*)(x + (size_t)s1 * 128 + c0);
    float2 v2 = *(const float2*)(x + (size_t)s2 * 128 + c0);
    float2 v3 = *(const float2*)(x + (size_t)s3 * 128 + c0);
    acc.x = fmaf(w0, v0.x, acc.x); acc.y = fmaf(w0, v0.y, acc.y);
    acc.x = fmaf(w1, v1.x, acc.x); acc.y = fmaf(w1, v1.y, acc.y);
    acc.x = fmaf(w2, v2.x, acc.x); acc.y = fmaf(w2, v2.y, acc.y);
    acc.x = fmaf(w3, v3.x, acc.x); acc.y = fmaf(w3, v3.y, acc.y);
  }
  for (; j < jend; ++j) {
    int e = perm[j];
    int s = ei[e];
    float w = ew[e];
    float2 v = *(const float2*)(x + (size_t)s * 128 + c0);
    acc.x = fmaf(w, v.x, acc.x); acc.y = fmaf(w, v.y, acc.y);
  }
  *(float2*)(agg + (size_t)d * 128 + c0) = acc;
}

extern "C" void kernel_launch(void* const* d_in, const int* in_sizes, int n_in,
                              void* d_out, int out_size, void* d_ws, size_t ws_size,
                              hipStream_t stream) {
  const float* features = (const float*)d_in[0];
  const int* ei = (const int*)d_in[1];   // [2, E] int32
  const float* ew = (const float*)d_in[2];
  const float* Wp = (const float*)d_in[3];
  const float* bp = (const float*)d_in[4];
  const float* Wa = (const float*)d_in[5];
  const float* ba = (const float*)d_in[6];

  const int N = in_sizes[0] / 256;  // 50000
  const int E = in_sizes[1] / 2;    // 800000

  float* out = (float*)d_out;
  float* x   = out;                 // [N,128] scratch lives in d_out until GEMM2

  // Workspace layout (256B-aligned):
  char* ws = (char*)d_ws;
  float* agg   = (float*)ws;                                   // N*128 f32 = 25.6 MB
  size_t o = (size_t)N * 128 * sizeof(float);
  o = (o + 255) & ~(size_t)255;
  int* cnt     = (int*)(ws + o); o += (size_t)N * 4;
  o = (o + 255) & ~(size_t)255;
  int* off     = (int*)(ws + o); o += (size_t)(N + 1) * 4;
  o = (o + 255) & ~(size_t)255;
  int* cursor  = (int*)(ws + o); o += (size_t)N * 4;
  o = (o + 255) & ~(size_t)255;
  int* bsum    = (int*)(ws + o); o += (size_t)256 * 4;
  o = (o + 255) & ~(size_t)255;
  int* perm    = (int*)(ws + o); o += (size_t)E * 4;

  const int nb = (N + 255) / 256;   // 196 scan blocks

  // counters must be zeroed every call (ws never re-poisoned between replays).
  hipMemsetAsync(cnt, 0, (size_t)N * sizeof(int), stream);

  // 1) x = features @ W_proj + b_proj
  gemm_lds<256, false><<<(N + 63) / 64, 256, 0, stream>>>(features, Wp, bp, x, N);

  // 2) CSR build by dst (count -> hierarchical scan -> fill)
  edge_count<<<1024, 256, 0, stream>>>(ei, cnt, E);
  block_sums<<<nb, 256, 0, stream>>>(cnt, bsum, N);
  scan_bsum<<<1, 256, 0, stream>>>(bsum, nb);
  scan_fin<<<nb, 256, 0, stream>>>(cnt, bsum, off, cursor, N, E);
  edge_fill<<<1024, 256, 0, stream>>>(ei, cursor, perm, E);

  // 3) agg[d] = sum_{e: dst=d} w_e * x[src_e]   (register accumulate, no atomics)
  gather_agg<<<(N + 3) / 4, 256, 0, stream>>>(x, ei, ew, off, perm, agg, N, E);

  // 4) out = relu(agg @ W_agg + b_agg)   (overwrites the x scratch)
  gemm_lds<128, true><<<(N + 63) / 64, 256, 0, stream>>>(agg, Wa, ba, out, N);
}